// Round 8
// baseline (295.147 us; speedup 1.0000x reference)
//
#include <hip/hip_runtime.h>
#include <hip/hip_bf16.h>

#define DM 1024
#define TT 2048
#define NH 16
#define DH 64
#define HD 4096

typedef __attribute__((ext_vector_type(4))) float f32x4;
typedef __attribute__((ext_vector_type(8))) short s16x8;
typedef __attribute__((ext_vector_type(4))) short s16x4;

static __device__ __forceinline__ short f2bf(float f) {
  __hip_bfloat16 h = __float2bfloat16(f);
  return *reinterpret_cast<short*>(&h);
}

typedef const __attribute__((address_space(1))) char* gas1_t;
typedef __attribute__((address_space(3))) char* las3_t;
static __device__ __forceinline__ void glds16(const void* g, void* l) {
  __builtin_amdgcn_global_load_lds((gas1_t)g, (las3_t)l, 16, 0, 0);
}

// ---------------- weight transpose + fp32->bf16 convert: in[K][N] -> out[N][K]
__global__ __launch_bounds__(256) void transpose_cvt_k(
    const float* __restrict__ in, short* __restrict__ out, int K, int N)
{
  __shared__ float tile[32][33];
  const int n0 = blockIdx.x * 32, k0 = blockIdx.y * 32;
  const int tx = threadIdx.x & 31, ty = threadIdx.x >> 5;
#pragma unroll
  for (int i = 0; i < 4; ++i)
    tile[ty + i * 8][tx] = in[(size_t)(k0 + ty + i * 8) * N + n0 + tx];
  __syncthreads();
#pragma unroll
  for (int i = 0; i < 4; ++i) {
    int n = ty + i * 8;
    out[(size_t)(n0 + n) * K + k0 + tx] = f2bf(tile[tx][n]);
  }
}

// ---------------- LayerNorm: fp32 in -> bf16 out, one block per row (D=1024)
__global__ __launch_bounds__(256) void ln_k(
    const float* __restrict__ x, const float* __restrict__ g,
    const float* __restrict__ b, short* __restrict__ out)
{
  const int row = blockIdx.x;
  const int tid = threadIdx.x;
  const float4 v = ((const float4*)(x + (size_t)row * DM))[tid];
  float s = v.x + v.y + v.z + v.w;
  float q = v.x * v.x + v.y * v.y + v.z * v.z + v.w * v.w;
#pragma unroll
  for (int off = 1; off < 64; off <<= 1) {
    s += __shfl_xor(s, off);
    q += __shfl_xor(q, off);
  }
  __shared__ float ss[4], sq[4];
  const int wave = tid >> 6;
  if ((tid & 63) == 0) { ss[wave] = s; sq[wave] = q; }
  __syncthreads();
  s = ss[0] + ss[1] + ss[2] + ss[3];
  q = sq[0] + sq[1] + sq[2] + sq[3];
  const float mu = s * (1.0f / DM);
  const float var = q * (1.0f / DM) - mu * mu;
  const float rs = rsqrtf(var + 1e-5f);
  const float4 gv = ((const float4*)g)[tid];
  const float4 bv = ((const float4*)b)[tid];
  s16x4 o;
  o[0] = f2bf((v.x - mu) * rs * gv.x + bv.x);
  o[1] = f2bf((v.y - mu) * rs * gv.y + bv.y);
  o[2] = f2bf((v.z - mu) * rs * gv.z + bv.z);
  o[3] = f2bf((v.w - mu) * rs * gv.w + bv.w);
  *(s16x4*)(out + (size_t)row * DM + tid * 4) = o;
}

// ---------------- GEMM: C[M][N] = A[M][K](bf16) * B^T  (B stored [N][K] bf16)
// 3-buffer LDS ring, stage 2 tiles ahead, counted vmcnt (T4) + raw s_barrier:
// at each barrier only the next-next tile's loads remain in flight.
// EPI: 1 = +bias +res(fp32) -> fp32      (attn tail -> x1, fc2 -> d_out)
//      2 = +bias, exact GELU -> bf16     (MLP fc1)
//      3 = QKV split: Q(pre-scaled by 0.125*log2e),K -> [bh][t][64]; V -> [bh][64][t]
template<int EPI, int BN>
__global__ __launch_bounds__(256) void gemm_bt(
    const short* __restrict__ A, const short* __restrict__ B,
    const float* __restrict__ bias, const float* __restrict__ res,
    float* __restrict__ outF, short* __restrict__ outB,
    short* __restrict__ outK, short* __restrict__ outV,
    int M, int N, int K)
{
  constexpr int MR = (BN == 128) ? 4 : 2;     // m-fragments per wave
  __shared__ short As[3][128 * 32];
  __shared__ short Bs[3][BN * 32];
  const int tid = threadIdx.x;
  const int wave = tid >> 6, lane = tid & 63;
  const int l15 = lane & 15, lhi = lane >> 4;
  const int bm = blockIdx.x, bn = blockIdx.y;
  const int wr = (BN == 128) ? (wave >> 1) : wave;
  const int wc = (BN == 128) ? (wave & 1) : 0;
  f32x4 acc[MR][4] = {};

  const int sr = wave * 16 + (lane >> 2);
  const int schunk = ((lane & 3) ^ ((lane >> 3) & 3)) * 16;  // bytes
  const char* gA = (const char*)(A + (size_t)(bm * 128 + sr) * K) + schunk;
  const char* gB = (const char*)(B + (size_t)(bn * BN + sr) * K) + schunk;
  const size_t rowstep = (size_t)64 * K * 2;

  const int NK = K >> 5;
  const int rsw = (l15 >> 1) & 3;             // read-side row swizzle bits
  const int achunk = (lhi ^ rsw) << 4;        // physical chunk byte offset

  auto stage = [&](int buf, int kt) {
    const size_t koff = (size_t)kt * 64;
    char* lA = (char*)As[buf] + wave * 1024;
    glds16(gA + koff, lA);
    glds16(gA + koff + rowstep, lA + 4096);
    char* lB = (char*)Bs[buf] + wave * 1024;
    glds16(gB + koff, lB);
    if (BN == 128) glds16(gB + koff + rowstep, lB + 4096);
  };
  auto wait_cnt = [&]() {   // keep exactly one stage (next-next tile) in flight
    if constexpr (BN == 128) asm volatile("s_waitcnt vmcnt(4)" ::: "memory");
    else                     asm volatile("s_waitcnt vmcnt(3)" ::: "memory");
  };

  stage(0, 0);
  stage(1, 1);
  wait_cnt();                                 // buf0 complete, buf1 in flight
  __builtin_amdgcn_s_barrier();

  int cur = 0;
  for (int kt = 0; kt < NK; ++kt) {
    if (kt + 2 < NK) {
      int nxt = cur + 2; if (nxt >= 3) nxt -= 3;
      stage(nxt, kt + 2);
    }
    s16x8 af[MR], bfv[4];
    const char* Ab = (const char*)As[cur];
    const char* Bb = (const char*)Bs[cur];
#pragma unroll
    for (int m = 0; m < MR; ++m) {
      const int row = wr * (MR * 16) + m * 16 + l15;
      af[m] = *(const s16x8*)(Ab + row * 64 + achunk);
    }
#pragma unroll
    for (int n = 0; n < 4; ++n) {
      const int row = wc * 64 + n * 16 + l15;
      bfv[n] = *(const s16x8*)(Bb + row * 64 + achunk);
    }
    __builtin_amdgcn_s_setprio(1);
#pragma unroll
    for (int m = 0; m < MR; ++m)
#pragma unroll
      for (int n = 0; n < 4; ++n)
        acc[m][n] = __builtin_amdgcn_mfma_f32_16x16x32_bf16(af[m], bfv[n], acc[m][n], 0, 0, 0);
    __builtin_amdgcn_s_setprio(0);
    if (kt + 2 < NK) wait_cnt();              // next buf ready; next-next in flight
    else asm volatile("s_waitcnt vmcnt(0)" ::: "memory");
    __builtin_amdgcn_s_barrier();
    ++cur; if (cur >= 3) cur -= 3;
  }

  const int rowb = bm * 128 + wr * (MR * 16);
  const int colb = bn * BN + wc * 64;
#pragma unroll
  for (int m = 0; m < MR; ++m) {
#pragma unroll
    for (int n = 0; n < 4; ++n) {
      if (EPI == 3) {
        const int col0 = colb + n * 16;
        const int h = col0 / 192;
        const int c0 = col0 - h * 192;
        const int region = c0 >> 6;           // 0=Q, 1=K, 2=V
        const int d = (c0 & 63) + l15;
        const int row0 = rowb + m * 16 + lhi * 4;
        const int bb = row0 >> 11, tl0 = row0 & 2047;
        const size_t bh = (size_t)bb * NH + h;
        if (region == 2) {
          s16x4 pk;
#pragma unroll
          for (int rr = 0; rr < 4; ++rr) pk[rr] = f2bf(acc[m][n][rr]);
          *(s16x4*)(outV + (bh * 64 + d) * TT + tl0) = pk;
        } else {
          short* dst = (region == 0) ? outB : outK;
          const float qs = (region == 0) ? 0.18033688011112042f : 1.0f;  // 0.125*log2(e)
#pragma unroll
          for (int rr = 0; rr < 4; ++rr)
            dst[(bh * TT + tl0 + rr) * 64 + d] = f2bf(acc[m][n][rr] * qs);
        }
      } else {
        const int col = colb + n * 16 + l15;
        const float bv = bias[col];
#pragma unroll
        for (int rr = 0; rr < 4; ++rr) {
          const int row = rowb + m * 16 + lhi * 4 + rr;
          float v = acc[m][n][rr] + bv;
          if (EPI == 1) v += res[(size_t)row * N + col];
          if (EPI == 2) v = 0.5f * v * (1.0f + erff(v * 0.70710678118f));
          if (EPI == 1) outF[(size_t)row * N + col] = v;
          else outB[(size_t)row * N + col] = f2bf(v);
        }
      }
    }
  }
}

// ---------------- flash attention v4: swapped-QK^T, 32 q/wave, LDS-staged K/V
// (KVBLK=128), padded (conflict-free) per-wave P roundtrip.
// Q(pre-scaled),K: [bh][t][64] bf16;  V^T: [bh][64][t] bf16;  out: [b*T][1024]
#define PSTRIDE 272                     // 256B row + 16B pad (bank-shift 4/row)
#define PFRAG   4352                    // 16 * PSTRIDE
__global__ __launch_bounds__(256, 2) void attn_k(
    const short* __restrict__ Qb, const short* __restrict__ Kb,
    const short* __restrict__ Vtb, const int* __restrict__ mask,
    short* __restrict__ outp)
{
  const int tid = threadIdx.x, wave = tid >> 6, lane = tid & 63;
  const int l15 = lane & 15, lhi = lane >> 4;
  // grid 512: lb = qb*32 + bh  ->  lb%8 = bh%8 (all q-blocks of a bh on one XCD)
  const int lb = blockIdx.x;
  const int bh = lb & 31, qb = lb >> 5;
  const int b = bh >> 4, h = bh & 15;
  const int qw = qb * 128 + wave * 32;        // this wave's first q row

  __shared__ short Ks[128 * 64];              // 16 KB
  __shared__ short Vt[64 * 128];              // 16 KB
  __shared__ char Ps[4 * 2 * PFRAG];          // 34 KB, per-wave x 2 frags

  // Q B-fragments: frag f covers q = qw + f*16 + l15
  const short* qb0 = Qb + ((size_t)bh * TT + qw + l15) * 64;
  const s16x8 aq00 = *(const s16x8*)(qb0 + lhi * 8);
  const s16x8 aq01 = *(const s16x8*)(qb0 + 32 + lhi * 8);
  const s16x8 aq10 = *(const s16x8*)(qb0 + 16 * 64 + lhi * 8);
  const s16x8 aq11 = *(const s16x8*)(qb0 + 16 * 64 + 32 + lhi * 8);

  f32x4 o[2][4] = {};
  float mrow[2] = {-1e30f, -1e30f};
  float lrow[2] = {0.f, 0.f};

  // staging geometry (bank-balanced, audited)
  const int kr_s = tid >> 1, kc_s = (tid & 1) * 32;   // K: 128 rows x 64 cols
  const int ksw = (kr_s & 7) << 4;
  const int vr_s = tid >> 2, vc_s = (tid & 3) * 32;   // Vt: 64 rows x 128 cols
  const int vsw = (vr_s & 7) << 4;

  const short* kgb = Kb + (size_t)bh * TT * 64 + (size_t)kr_s * 64 + kc_s;
  const short* vgb = Vtb + ((size_t)bh * 64 + vr_s) * TT + vc_s;

  s16x8 kpre[4], vpre[4];
#pragma unroll
  for (int j = 0; j < 4; ++j) {
    kpre[j] = *(const s16x8*)(kgb + j * 8);
    vpre[j] = *(const s16x8*)(vgb + j * 8);
  }
  int m0 = mask[b * TT + lane], m1 = mask[b * TT + 64 + lane];

  char* pb0 = Ps + (wave * 2) * PFRAG + l15 * PSTRIDE;
  char* pb1 = pb0 + PFRAG;

  for (int t0 = 0; t0 < TT; t0 += 128) {
    // ---- stage current tile regs -> LDS (swizzled rows)
    char* krow = (char*)Ks + kr_s * 128;
#pragma unroll
    for (int j = 0; j < 4; ++j)
      *(s16x8*)(krow + ((kc_s * 2 + j * 16) ^ ksw)) = kpre[j];
    char* vrow = (char*)Vt + vr_s * 256;
#pragma unroll
    for (int j = 0; j < 4; ++j)
      *(s16x8*)(vrow + ((vc_s * 2 + j * 16) ^ vsw)) = vpre[j];
    __syncthreads();

    const unsigned long long mb0 = __ballot(m0 != 0);
    const unsigned long long mb1 = __ballot(m1 != 0);
    const bool full = (mb0 & mb1) == ~0ULL;

    // ---- prefetch next tile (hidden under compute)
    if (t0 + 128 < TT) {
      const short* kg = kgb + (size_t)(t0 + 128) * 64;
      const short* vg = vgb + t0 + 128;
#pragma unroll
      for (int j = 0; j < 4; ++j) {
        kpre[j] = *(const s16x8*)(kg + j * 8);
        vpre[j] = *(const s16x8*)(vg + j * 8);
      }
      m0 = mask[b * TT + t0 + 128 + lane];
      m1 = mask[b * TT + t0 + 192 + lane];
    }

    // ---- S^T = K Q^T : sv[n][r]: key = n*16 + lhi*4 + r, q = l15 (log2 units)
    f32x4 sv0[8], sv1[8];
#pragma unroll
    for (int n = 0; n < 8; ++n) {
      const int row = n * 16 + l15;
      const int sw = (row & 7) << 4;
      const char* kr = (const char*)Ks + row * 128;
      const s16x8 a0 = *(const s16x8*)(kr + ((lhi * 16) ^ sw));
      const s16x8 a1 = *(const s16x8*)(kr + ((64 + lhi * 16) ^ sw));
      f32x4 z0 = {}, z1 = {};
      z0 = __builtin_amdgcn_mfma_f32_16x16x32_bf16(a0, aq00, z0, 0, 0, 0);
      z0 = __builtin_amdgcn_mfma_f32_16x16x32_bf16(a1, aq01, z0, 0, 0, 0);
      z1 = __builtin_amdgcn_mfma_f32_16x16x32_bf16(a0, aq10, z1, 0, 0, 0);
      z1 = __builtin_amdgcn_mfma_f32_16x16x32_bf16(a1, aq11, z1, 0, 0, 0);
      sv0[n] = z0; sv1[n] = z1;
    }

    // ---- mask (slow path only)
    if (!full) {
#pragma unroll
      for (int n = 0; n < 8; ++n) {
        const unsigned long long mbn = (n < 4) ? mb0 : mb1;
        const unsigned nib = (unsigned)(mbn >> ((n & 3) * 16 + lhi * 4)) & 0xF;
#pragma unroll
        for (int rr = 0; rr < 4; ++rr)
          if (!((nib >> rr) & 1)) { sv0[n][rr] = -3e38f; sv1[n][rr] = -3e38f; }
      }
    }

    // ---- per-frag online softmax (log2 domain), defer-max
#pragma unroll
    for (int f = 0; f < 2; ++f) {
      f32x4* sv = f ? sv1 : sv0;
      float mx0 = -3e38f, mx1 = -3e38f, mx2 = -3e38f, mx3 = -3e38f;
#pragma unroll
      for (int n = 0; n < 8; ++n) {
        mx0 = fmaxf(mx0, sv[n][0]); mx1 = fmaxf(mx1, sv[n][1]);
        mx2 = fmaxf(mx2, sv[n][2]); mx3 = fmaxf(mx3, sv[n][3]);
      }
      float mx = fmaxf(fmaxf(mx0, mx1), fmaxf(mx2, mx3));
      mx = fmaxf(mx, __shfl_xor(mx, 16));
      mx = fmaxf(mx, __shfl_xor(mx, 32));
      if (__any(mx > mrow[f] + 8.0f)) {
        const float mn = fmaxf(mrow[f], mx);
        const float alpha = exp2f(mrow[f] - mn);
        mrow[f] = mn;
        lrow[f] *= alpha;
        float ar[4];
#pragma unroll
        for (int rr = 0; rr < 4; ++rr) ar[rr] = __shfl(alpha, lhi * 4 + rr);
#pragma unroll
        for (int db = 0; db < 4; ++db)
#pragma unroll
          for (int rr = 0; rr < 4; ++rr) o[f][db][rr] *= ar[rr];
      }
      float s0 = 0.f, s1 = 0.f, s2 = 0.f, s3 = 0.f;
#pragma unroll
      for (int n = 0; n < 8; ++n) {
        sv[n][0] = exp2f(sv[n][0] - mrow[f]); s0 += sv[n][0];
        sv[n][1] = exp2f(sv[n][1] - mrow[f]); s1 += sv[n][1];
        sv[n][2] = exp2f(sv[n][2] - mrow[f]); s2 += sv[n][2];
        sv[n][3] = exp2f(sv[n][3] - mrow[f]); s3 += sv[n][3];
      }
      float sum = (s0 + s1) + (s2 + s3);
      sum += __shfl_xor(sum, 16);
      sum += __shfl_xor(sum, 32);
      lrow[f] += sum;
    }

    // ---- P -> per-wave LDS, padded layout (no swizzle, conflict-free)
#pragma unroll
    for (int n = 0; n < 8; ++n) {
      s16x4 p0, p1;
#pragma unroll
      for (int rr = 0; rr < 4; ++rr) { p0[rr] = f2bf(sv0[n][rr]); p1[rr] = f2bf(sv1[n][rr]); }
      *(s16x4*)(pb0 + n * 32 + lhi * 8) = p0;
      *(s16x4*)(pb1 + n * 32 + lhi * 8) = p1;
    }
    asm volatile("s_waitcnt lgkmcnt(0)" ::: "memory");
    __builtin_amdgcn_sched_barrier(0);
    s16x8 ap0[4], ap1[4];
#pragma unroll
    for (int ks = 0; ks < 4; ++ks) {
      ap0[ks] = *(const s16x8*)(pb0 + ks * 64 + lhi * 16);
      ap1[ks] = *(const s16x8*)(pb1 + ks * 64 + lhi * 16);
    }

    // ---- PV: V B-frags from LDS, each read feeds both q-frags
#pragma unroll
    for (int db = 0; db < 4; ++db) {
      const int d = db * 16 + l15;
      const int swv = (d & 7) << 4;
      const char* vr2 = (const char*)Vt + d * 256;
#pragma unroll
      for (int ks = 0; ks < 4; ++ks) {
        const s16x8 bv = *(const s16x8*)(vr2 + ((ks * 64 + lhi * 16) ^ swv));
        o[0][db] = __builtin_amdgcn_mfma_f32_16x16x32_bf16(ap0[ks], bv, o[0][db], 0, 0, 0);
        o[1][db] = __builtin_amdgcn_mfma_f32_16x16x32_bf16(ap1[ks], bv, o[1][db], 0, 0, 0);
      }
    }
    __syncthreads();
  }

  // ---- normalize + write concat layout [b*T][1024], col = h*64 + d
#pragma unroll
  for (int f = 0; f < 2; ++f) {
    float lr[4];
#pragma unroll
    for (int rr = 0; rr < 4; ++rr) lr[rr] = __shfl(lrow[f], lhi * 4 + rr);
#pragma unroll
    for (int db = 0; db < 4; ++db) {
#pragma unroll
      for (int rr = 0; rr < 4; ++rr) {
        const int qg = qw + f * 16 + lhi * 4 + rr;
        const int cg = h * 64 + db * 16 + l15;
        outp[(size_t)(b * TT + qg) * DM + cg] = f2bf(o[f][db][rr] / lr[rr]);
      }
    }
  }
}

extern "C" void kernel_launch(void* const* d_in, const int* in_sizes, int n_in,
                              void* d_out, int out_size, void* d_ws, size_t ws_size,
                              hipStream_t stream)
{
  const float* x      = (const float*)d_in[0];
  const int*   mask   = (const int*)d_in[1];
  const float* w_qkv  = (const float*)d_in[2];
  const float* w_tail = (const float*)d_in[3];
  const float* b_tail = (const float*)d_in[4];
  const float* ln1g   = (const float*)d_in[5];
  const float* ln1b   = (const float*)d_in[6];
  const float* ln2g   = (const float*)d_in[7];
  const float* ln2b   = (const float*)d_in[8];
  const float* w1     = (const float*)d_in[9];
  const float* b1     = (const float*)d_in[10];
  const float* w2     = (const float*)d_in[11];
  const float* b2     = (const float*)d_in[12];

  char* ws = (char*)d_ws;
  size_t off = 0;
  auto take = [&](size_t bytes) {
    char* p = ws + off;
    off += (bytes + 255) & ~(size_t)255;
    return p;
  };
  short* slotW = (short*)take((size_t)4096 * 2048 * 2);     // 16 MB (wqkvT/wtailT/w1T/w2T)
  short* slotZ = (short*)take((size_t)4096 * 1024 * 2);     //  8 MB (z1 / attn-out / z2)
  short* qb    = (short*)take((size_t)32 * 2048 * 64 * 2);  //  8 MB [bh][t][64]
  short* kb    = (short*)take((size_t)32 * 2048 * 64 * 2);  //  8 MB
  short* vtb   = (short*)take((size_t)32 * 64 * 2048 * 2);  //  8 MB [bh][64][t]
  float* x1    = (float*)take((size_t)4096 * 1024 * 4);     // 16 MB
  short* hbuf  = (short*)take((size_t)4096 * 4096 * 2);     // 32 MB

  // LN1 -> QKV projection (split layout, Q pre-scaled)
  transpose_cvt_k<<<dim3(3072 / 32, 1024 / 32), 256, 0, stream>>>(w_qkv, slotW, 1024, 3072);
  ln_k<<<4096, 256, 0, stream>>>(x, ln1g, ln1b, slotZ);
  gemm_bt<3, 128><<<dim3(32, 24), 256, 0, stream>>>(slotZ, slotW, nullptr, nullptr,
                                                    nullptr, qb, kb, vtb, 4096, 3072, 1024);
  // attention (slotZ reused for attn output)
  attn_k<<<512, 256, 0, stream>>>(qb, kb, vtb, mask, slotZ);
  // tail projection + residual -> x1 (fp32)
  transpose_cvt_k<<<dim3(1024 / 32, 1024 / 32), 256, 0, stream>>>(w_tail, slotW, 1024, 1024);
  gemm_bt<1, 64><<<dim3(32, 16), 256, 0, stream>>>(slotZ, slotW, b_tail, x,
                                                   x1, nullptr, nullptr, nullptr, 4096, 1024, 1024);
  // LN2 -> MLP
  ln_k<<<4096, 256, 0, stream>>>(x1, ln2g, ln2b, slotZ);
  transpose_cvt_k<<<dim3(4096 / 32, 1024 / 32), 256, 0, stream>>>(w1, slotW, 1024, 4096);
  gemm_bt<2, 128><<<dim3(32, 32), 256, 0, stream>>>(slotZ, slotW, b1, nullptr,
                                                    nullptr, hbuf, nullptr, nullptr, 4096, 4096, 1024);
  transpose_cvt_k<<<dim3(1024 / 32, 4096 / 32), 256, 0, stream>>>(w2, slotW, 4096, 1024);
  gemm_bt<1, 64><<<dim3(32, 16), 256, 0, stream>>>(hbuf, slotW, b2, x1,
                                                   (float*)d_out, nullptr, nullptr, nullptr, 4096, 1024, 4096);
}

// Round 9
// 284.457 us; speedup vs baseline: 1.0376x; 1.0376x over previous
//
#include <hip/hip_runtime.h>
#include <hip/hip_bf16.h>

#define DM 1024
#define TT 2048
#define NH 16
#define DH 64
#define HD 4096

typedef __attribute__((ext_vector_type(4))) float f32x4;
typedef __attribute__((ext_vector_type(8))) short s16x8;
typedef __attribute__((ext_vector_type(4))) short s16x4;

static __device__ __forceinline__ short f2bf(float f) {
  __hip_bfloat16 h = __float2bfloat16(f);
  return *reinterpret_cast<short*>(&h);
}

typedef const __attribute__((address_space(1))) char* gas1_t;
typedef __attribute__((address_space(3))) char* las3_t;
static __device__ __forceinline__ void glds16(const void* g, void* l) {
  __builtin_amdgcn_global_load_lds((gas1_t)g, (las3_t)l, 16, 0, 0);
}

// ---------------- weight transpose + fp32->bf16 convert: in[K][N] -> out[N][K]
__global__ __launch_bounds__(256) void transpose_cvt_k(
    const float* __restrict__ in, short* __restrict__ out, int K, int N)
{
  __shared__ float tile[32][33];
  const int n0 = blockIdx.x * 32, k0 = blockIdx.y * 32;
  const int tx = threadIdx.x & 31, ty = threadIdx.x >> 5;
#pragma unroll
  for (int i = 0; i < 4; ++i)
    tile[ty + i * 8][tx] = in[(size_t)(k0 + ty + i * 8) * N + n0 + tx];
  __syncthreads();
#pragma unroll
  for (int i = 0; i < 4; ++i) {
    int n = ty + i * 8;
    out[(size_t)(n0 + n) * K + k0 + tx] = f2bf(tile[tx][n]);
  }
}

// ---------------- LayerNorm: fp32 in -> bf16 out, one block per row (D=1024)
__global__ __launch_bounds__(256) void ln_k(
    const float* __restrict__ x, const float* __restrict__ g,
    const float* __restrict__ b, short* __restrict__ out)
{
  const int row = blockIdx.x;
  const int tid = threadIdx.x;
  const float4 v = ((const float4*)(x + (size_t)row * DM))[tid];
  float s = v.x + v.y + v.z + v.w;
  float q = v.x * v.x + v.y * v.y + v.z * v.z + v.w * v.w;
#pragma unroll
  for (int off = 1; off < 64; off <<= 1) {
    s += __shfl_xor(s, off);
    q += __shfl_xor(q, off);
  }
  __shared__ float ss[4], sq[4];
  const int wave = tid >> 6;
  if ((tid & 63) == 0) { ss[wave] = s; sq[wave] = q; }
  __syncthreads();
  s = ss[0] + ss[1] + ss[2] + ss[3];
  q = sq[0] + sq[1] + sq[2] + sq[3];
  const float mu = s * (1.0f / DM);
  const float var = q * (1.0f / DM) - mu * mu;
  const float rs = rsqrtf(var + 1e-5f);
  const float4 gv = ((const float4*)g)[tid];
  const float4 bv = ((const float4*)b)[tid];
  s16x4 o;
  o[0] = f2bf((v.x - mu) * rs * gv.x + bv.x);
  o[1] = f2bf((v.y - mu) * rs * gv.y + bv.y);
  o[2] = f2bf((v.z - mu) * rs * gv.z + bv.z);
  o[3] = f2bf((v.w - mu) * rs * gv.w + bv.w);
  *(s16x4*)(out + (size_t)row * DM + tid * 4) = o;
}

// ---------------- GEMM: C[M][N] = A[M][K](bf16) * B^T  (B stored [N][K] bf16)
// 2-phase double-buffered LDS pipeline; chunk-swizzled LDS. (r7 known-good)
// EPI: 1 = +bias +res(fp32) -> fp32      (attn tail -> x1, fc2 -> d_out)
//      2 = +bias, exact GELU -> bf16     (MLP fc1)
//      3 = QKV split: Q(pre-scaled by 0.125*log2e),K -> [bh][t][64]; V -> [bh][64][t]
template<int EPI, int BN>
__global__ __launch_bounds__(256) void gemm_bt(
    const short* __restrict__ A, const short* __restrict__ B,
    const float* __restrict__ bias, const float* __restrict__ res,
    float* __restrict__ outF, short* __restrict__ outB,
    short* __restrict__ outK, short* __restrict__ outV,
    int M, int N, int K)
{
  constexpr int MR = (BN == 128) ? 4 : 2;     // m-fragments per wave
  __shared__ short As[2][128 * 32];
  __shared__ short Bs[2][BN * 32];
  const int tid = threadIdx.x;
  const int wave = tid >> 6, lane = tid & 63;
  const int l15 = lane & 15, lhi = lane >> 4;
  const int bm = blockIdx.x, bn = blockIdx.y;
  const int wr = (BN == 128) ? (wave >> 1) : wave;
  const int wc = (BN == 128) ? (wave & 1) : 0;
  f32x4 acc[MR][4] = {};

  const int sr = wave * 16 + (lane >> 2);
  const int schunk = ((lane & 3) ^ ((lane >> 3) & 3)) * 16;  // bytes
  const char* gA = (const char*)(A + (size_t)(bm * 128 + sr) * K) + schunk;
  const char* gB = (const char*)(B + (size_t)(bn * BN + sr) * K) + schunk;
  const size_t rowstep = (size_t)64 * K * 2;

  const int NK = K >> 5;
  const int rsw = (l15 >> 1) & 3;             // read-side row swizzle bits
  const int achunk = (lhi ^ rsw) << 4;        // physical chunk byte offset

  auto stage = [&](int buf, int kt) {
    const size_t koff = (size_t)kt * 64;
    char* lA = (char*)As[buf] + wave * 1024;
    glds16(gA + koff, lA);
    glds16(gA + koff + rowstep, lA + 4096);
    char* lB = (char*)Bs[buf] + wave * 1024;
    glds16(gB + koff, lB);
    if (BN == 128) glds16(gB + koff + rowstep, lB + 4096);
  };

  stage(0, 0);
  __syncthreads();
  int cur = 0;
  for (int kt = 0; kt < NK; ++kt) {
    if (kt + 1 < NK) stage(cur ^ 1, kt + 1);
    s16x8 af[MR], bfv[4];
#pragma unroll
    for (int m = 0; m < MR; ++m) {
      const int row = wr * (MR * 16) + m * 16 + l15;
      af[m] = *(const s16x8*)((const char*)As[cur] + row * 64 + achunk);
    }
#pragma unroll
    for (int n = 0; n < 4; ++n) {
      const int row = wc * 64 + n * 16 + l15;
      bfv[n] = *(const s16x8*)((const char*)Bs[cur] + row * 64 + achunk);
    }
#pragma unroll
    for (int m = 0; m < MR; ++m)
#pragma unroll
      for (int n = 0; n < 4; ++n)
        acc[m][n] = __builtin_amdgcn_mfma_f32_16x16x32_bf16(af[m], bfv[n], acc[m][n], 0, 0, 0);
    __syncthreads();
    cur ^= 1;
  }

  const int rowb = bm * 128 + wr * (MR * 16);
  const int colb = bn * BN + wc * 64;
#pragma unroll
  for (int m = 0; m < MR; ++m) {
#pragma unroll
    for (int n = 0; n < 4; ++n) {
      if (EPI == 3) {
        const int col0 = colb + n * 16;
        const int h = col0 / 192;
        const int c0 = col0 - h * 192;
        const int region = c0 >> 6;           // 0=Q, 1=K, 2=V
        const int d = (c0 & 63) + l15;
        const int row0 = rowb + m * 16 + lhi * 4;
        const int bb = row0 >> 11, tl0 = row0 & 2047;
        const size_t bh = (size_t)bb * NH + h;
        if (region == 2) {
          s16x4 pk;
#pragma unroll
          for (int rr = 0; rr < 4; ++rr) pk[rr] = f2bf(acc[m][n][rr]);
          *(s16x4*)(outV + (bh * 64 + d) * TT + tl0) = pk;
        } else {
          short* dst = (region == 0) ? outB : outK;
          const float qs = (region == 0) ? 0.18033688011112042f : 1.0f;  // 0.125*log2(e)
#pragma unroll
          for (int rr = 0; rr < 4; ++rr)
            dst[(bh * TT + tl0 + rr) * 64 + d] = f2bf(acc[m][n][rr] * qs);
        }
      } else {
        const int col = colb + n * 16 + l15;
        const float bv = bias[col];
#pragma unroll
        for (int rr = 0; rr < 4; ++rr) {
          const int row = rowb + m * 16 + lhi * 4 + rr;
          float v = acc[m][n][rr] + bv;
          if (EPI == 1) v += res[(size_t)row * N + col];
          if (EPI == 2) v = 0.5f * v * (1.0f + erff(v * 0.70710678118f));
          if (EPI == 1) outF[(size_t)row * N + col] = v;
          else outB[(size_t)row * N + col] = f2bf(v);
        }
      }
    }
  }
}

// ---------------- flash attention v5: swapped-QK^T, 32 q/wave, LDS-staged K/V
// (KVBLK=128), time-shared per-wave P buffer (halves P LDS -> 3 blocks/CU).
// Q(pre-scaled),K: [bh][t][64] bf16;  V^T: [bh][64][t] bf16;  out: [b*T][1024]
#define PSTRIDE 272                     // 256B row + 16B pad (bank-shift 4/row)
#define PFRAG   4352                    // 16 * PSTRIDE
__global__ __launch_bounds__(256, 2) void attn_k(
    const short* __restrict__ Qb, const short* __restrict__ Kb,
    const short* __restrict__ Vtb, const int* __restrict__ mask,
    short* __restrict__ outp)
{
  const int tid = threadIdx.x, wave = tid >> 6, lane = tid & 63;
  const int l15 = lane & 15, lhi = lane >> 4;
  // grid 512: lb = qb*32 + bh  ->  lb%8 = bh%8 (all q-blocks of a bh on one XCD)
  const int lb = blockIdx.x;
  const int bh = lb & 31, qb = lb >> 5;
  const int b = bh >> 4, h = bh & 15;
  const int qw = qb * 128 + wave * 32;        // this wave's first q row

  __shared__ short Ks[128 * 64];              // 16 KB
  __shared__ short Vt[64 * 128];              // 16 KB
  __shared__ char Ps[4 * PFRAG];              // 17 KB, per-wave, frag time-shared

  // Q B-fragments: frag f covers q = qw + f*16 + l15
  const short* qb0 = Qb + ((size_t)bh * TT + qw + l15) * 64;
  const s16x8 aq00 = *(const s16x8*)(qb0 + lhi * 8);
  const s16x8 aq01 = *(const s16x8*)(qb0 + 32 + lhi * 8);
  const s16x8 aq10 = *(const s16x8*)(qb0 + 16 * 64 + lhi * 8);
  const s16x8 aq11 = *(const s16x8*)(qb0 + 16 * 64 + 32 + lhi * 8);

  f32x4 o[2][4] = {};
  float mrow[2] = {-1e30f, -1e30f};
  float lrow[2] = {0.f, 0.f};

  // staging geometry (bank-balanced, audited)
  const int kr_s = tid >> 1, kc_s = (tid & 1) * 32;   // K: 128 rows x 64 cols
  const int ksw = (kr_s & 7) << 4;
  const int vr_s = tid >> 2, vc_s = (tid & 3) * 32;   // Vt: 64 rows x 128 cols
  const int vsw = (vr_s & 7) << 4;

  const short* kgb = Kb + (size_t)bh * TT * 64 + (size_t)kr_s * 64 + kc_s;
  const short* vgb = Vtb + ((size_t)bh * 64 + vr_s) * TT + vc_s;

  s16x8 kpre[4], vpre[4];
#pragma unroll
  for (int j = 0; j < 4; ++j) {
    kpre[j] = *(const s16x8*)(kgb + j * 8);
    vpre[j] = *(const s16x8*)(vgb + j * 8);
  }
  int m0 = mask[b * TT + lane], m1 = mask[b * TT + 64 + lane];

  char* pb = Ps + wave * PFRAG + l15 * PSTRIDE;

  for (int t0 = 0; t0 < TT; t0 += 128) {
    // ---- stage current tile regs -> LDS (swizzled rows)
    char* krow = (char*)Ks + kr_s * 128;
#pragma unroll
    for (int j = 0; j < 4; ++j)
      *(s16x8*)(krow + ((kc_s * 2 + j * 16) ^ ksw)) = kpre[j];
    char* vrow = (char*)Vt + vr_s * 256;
#pragma unroll
    for (int j = 0; j < 4; ++j)
      *(s16x8*)(vrow + ((vc_s * 2 + j * 16) ^ vsw)) = vpre[j];
    __syncthreads();

    const unsigned long long mb0 = __ballot(m0 != 0);
    const unsigned long long mb1 = __ballot(m1 != 0);
    const bool full = (mb0 & mb1) == ~0ULL;

    // ---- prefetch next tile (hidden under compute)
    if (t0 + 128 < TT) {
      const short* kg = kgb + (size_t)(t0 + 128) * 64;
      const short* vg = vgb + t0 + 128;
#pragma unroll
      for (int j = 0; j < 4; ++j) {
        kpre[j] = *(const s16x8*)(kg + j * 8);
        vpre[j] = *(const s16x8*)(vg + j * 8);
      }
      m0 = mask[b * TT + t0 + 128 + lane];
      m1 = mask[b * TT + t0 + 192 + lane];
    }

    // ---- S^T = K Q^T : sv[n][r]: key = n*16 + lhi*4 + r, q = l15 (log2 units)
    f32x4 sv0[8], sv1[8];
    __builtin_amdgcn_s_setprio(1);
#pragma unroll
    for (int n = 0; n < 8; ++n) {
      const int row = n * 16 + l15;
      const int sw = (row & 7) << 4;
      const char* kr = (const char*)Ks + row * 128;
      const s16x8 a0 = *(const s16x8*)(kr + ((lhi * 16) ^ sw));
      const s16x8 a1 = *(const s16x8*)(kr + ((64 + lhi * 16) ^ sw));
      f32x4 z0 = {}, z1 = {};
      z0 = __builtin_amdgcn_mfma_f32_16x16x32_bf16(a0, aq00, z0, 0, 0, 0);
      z0 = __builtin_amdgcn_mfma_f32_16x16x32_bf16(a1, aq01, z0, 0, 0, 0);
      z1 = __builtin_amdgcn_mfma_f32_16x16x32_bf16(a0, aq10, z1, 0, 0, 0);
      z1 = __builtin_amdgcn_mfma_f32_16x16x32_bf16(a1, aq11, z1, 0, 0, 0);
      sv0[n] = z0; sv1[n] = z1;
    }
    __builtin_amdgcn_s_setprio(0);

    // ---- mask (slow path only)
    if (!full) {
#pragma unroll
      for (int n = 0; n < 8; ++n) {
        const unsigned long long mbn = (n < 4) ? mb0 : mb1;
        const unsigned nib = (unsigned)(mbn >> ((n & 3) * 16 + lhi * 4)) & 0xF;
#pragma unroll
        for (int rr = 0; rr < 4; ++rr)
          if (!((nib >> rr) & 1)) { sv0[n][rr] = -3e38f; sv1[n][rr] = -3e38f; }
      }
    }

    // ---- per-frag online softmax (log2 domain), defer-max
#pragma unroll
    for (int f = 0; f < 2; ++f) {
      f32x4* sv = f ? sv1 : sv0;
      float mx0 = -3e38f, mx1 = -3e38f, mx2 = -3e38f, mx3 = -3e38f;
#pragma unroll
      for (int n = 0; n < 8; ++n) {
        mx0 = fmaxf(mx0, sv[n][0]); mx1 = fmaxf(mx1, sv[n][1]);
        mx2 = fmaxf(mx2, sv[n][2]); mx3 = fmaxf(mx3, sv[n][3]);
      }
      float mx = fmaxf(fmaxf(mx0, mx1), fmaxf(mx2, mx3));
      mx = fmaxf(mx, __shfl_xor(mx, 16));
      mx = fmaxf(mx, __shfl_xor(mx, 32));
      if (__any(mx > mrow[f] + 8.0f)) {
        const float mn = fmaxf(mrow[f], mx);
        const float alpha = exp2f(mrow[f] - mn);
        mrow[f] = mn;
        lrow[f] *= alpha;
        float ar[4];
#pragma unroll
        for (int rr = 0; rr < 4; ++rr) ar[rr] = __shfl(alpha, lhi * 4 + rr);
#pragma unroll
        for (int db = 0; db < 4; ++db)
#pragma unroll
          for (int rr = 0; rr < 4; ++rr) o[f][db][rr] *= ar[rr];
      }
      float s0 = 0.f, s1 = 0.f, s2 = 0.f, s3 = 0.f;
#pragma unroll
      for (int n = 0; n < 8; ++n) {
        sv[n][0] = exp2f(sv[n][0] - mrow[f]); s0 += sv[n][0];
        sv[n][1] = exp2f(sv[n][1] - mrow[f]); s1 += sv[n][1];
        sv[n][2] = exp2f(sv[n][2] - mrow[f]); s2 += sv[n][2];
        sv[n][3] = exp2f(sv[n][3] - mrow[f]); s3 += sv[n][3];
      }
      float sum = (s0 + s1) + (s2 + s3);
      sum += __shfl_xor(sum, 16);
      sum += __shfl_xor(sum, 32);
      lrow[f] += sum;
    }

    // ---- P frag0 -> per-wave LDS (padded), read ap0; then frag1 reuses buffer.
    // Per-wave DS ops execute in order; sched_barrier(0) pins compiler order.
    s16x8 ap0[4], ap1[4];
#pragma unroll
    for (int n = 0; n < 8; ++n) {
      s16x4 p0;
#pragma unroll
      for (int rr = 0; rr < 4; ++rr) p0[rr] = f2bf(sv0[n][rr]);
      *(s16x4*)(pb + n * 32 + lhi * 8) = p0;
    }
    asm volatile("s_waitcnt lgkmcnt(0)" ::: "memory");
    __builtin_amdgcn_sched_barrier(0);
#pragma unroll
    for (int ks = 0; ks < 4; ++ks)
      ap0[ks] = *(const s16x8*)(pb + ks * 64 + lhi * 16);
    __builtin_amdgcn_sched_barrier(0);
#pragma unroll
    for (int n = 0; n < 8; ++n) {
      s16x4 p1;
#pragma unroll
      for (int rr = 0; rr < 4; ++rr) p1[rr] = f2bf(sv1[n][rr]);
      *(s16x4*)(pb + n * 32 + lhi * 8) = p1;
    }
    asm volatile("s_waitcnt lgkmcnt(0)" ::: "memory");
    __builtin_amdgcn_sched_barrier(0);
#pragma unroll
    for (int ks = 0; ks < 4; ++ks)
      ap1[ks] = *(const s16x8*)(pb + ks * 64 + lhi * 16);

    // ---- PV: V B-frags from LDS, each read feeds both q-frags
    __builtin_amdgcn_s_setprio(1);
#pragma unroll
    for (int db = 0; db < 4; ++db) {
      const int d = db * 16 + l15;
      const int swv = (d & 7) << 4;
      const char* vr2 = (const char*)Vt + d * 256;
#pragma unroll
      for (int ks = 0; ks < 4; ++ks) {
        const s16x8 bv = *(const s16x8*)(vr2 + ((ks * 64 + lhi * 16) ^ swv));
        o[0][db] = __builtin_amdgcn_mfma_f32_16x16x32_bf16(ap0[ks], bv, o[0][db], 0, 0, 0);
        o[1][db] = __builtin_amdgcn_mfma_f32_16x16x32_bf16(ap1[ks], bv, o[1][db], 0, 0, 0);
      }
    }
    __builtin_amdgcn_s_setprio(0);
    __syncthreads();
  }

  // ---- normalize + write concat layout [b*T][1024], col = h*64 + d
#pragma unroll
  for (int f = 0; f < 2; ++f) {
    float lr[4];
#pragma unroll
    for (int rr = 0; rr < 4; ++rr) lr[rr] = __shfl(lrow[f], lhi * 4 + rr);
#pragma unroll
    for (int db = 0; db < 4; ++db) {
#pragma unroll
      for (int rr = 0; rr < 4; ++rr) {
        const int qg = qw + f * 16 + lhi * 4 + rr;
        const int cg = h * 64 + db * 16 + l15;
        outp[(size_t)(b * TT + qg) * DM + cg] = f2bf(o[f][db][rr] / lr[rr]);
      }
    }
  }
}

extern "C" void kernel_launch(void* const* d_in, const int* in_sizes, int n_in,
                              void* d_out, int out_size, void* d_ws, size_t ws_size,
                              hipStream_t stream)
{
  const float* x      = (const float*)d_in[0];
  const int*   mask   = (const int*)d_in[1];
  const float* w_qkv  = (const float*)d_in[2];
  const float* w_tail = (const float*)d_in[3];
  const float* b_tail = (const float*)d_in[4];
  const float* ln1g   = (const float*)d_in[5];
  const float* ln1b   = (const float*)d_in[6];
  const float* ln2g   = (const float*)d_in[7];
  const float* ln2b   = (const float*)d_in[8];
  const float* w1     = (const float*)d_in[9];
  const float* b1     = (const float*)d_in[10];
  const float* w2     = (const float*)d_in[11];
  const float* b2     = (const float*)d_in[12];

  char* ws = (char*)d_ws;
  size_t off = 0;
  auto take = [&](size_t bytes) {
    char* p = ws + off;
    off += (bytes + 255) & ~(size_t)255;
    return p;
  };
  short* slotW = (short*)take((size_t)4096 * 2048 * 2);     // 16 MB (wqkvT/wtailT/w1T/w2T)
  short* slotZ = (short*)take((size_t)4096 * 1024 * 2);     //  8 MB (z1 / attn-out / z2)
  short* qb    = (short*)take((size_t)32 * 2048 * 64 * 2);  //  8 MB [bh][t][64]
  short* kb    = (short*)take((size_t)32 * 2048 * 64 * 2);  //  8 MB
  short* vtb   = (short*)take((size_t)32 * 64 * 2048 * 2);  //  8 MB [bh][64][t]
  float* x1    = (float*)take((size_t)4096 * 1024 * 4);     // 16 MB
  short* hbuf  = (short*)take((size_t)4096 * 4096 * 2);     // 32 MB

  // LN1 -> QKV projection (split layout, Q pre-scaled)
  transpose_cvt_k<<<dim3(3072 / 32, 1024 / 32), 256, 0, stream>>>(w_qkv, slotW, 1024, 3072);
  ln_k<<<4096, 256, 0, stream>>>(x, ln1g, ln1b, slotZ);
  gemm_bt<3, 128><<<dim3(32, 24), 256, 0, stream>>>(slotZ, slotW, nullptr, nullptr,
                                                    nullptr, qb, kb, vtb, 4096, 3072, 1024);
  // attention (slotZ reused for attn output)
  attn_k<<<512, 256, 0, stream>>>(qb, kb, vtb, mask, slotZ);
  // tail projection + residual -> x1 (fp32)
  transpose_cvt_k<<<dim3(1024 / 32, 1024 / 32), 256, 0, stream>>>(w_tail, slotW, 1024, 1024);
  gemm_bt<1, 64><<<dim3(32, 16), 256, 0, stream>>>(slotZ, slotW, b_tail, x,
                                                   x1, nullptr, nullptr, nullptr, 4096, 1024, 1024);
  // LN2 -> MLP
  ln_k<<<4096, 256, 0, stream>>>(x1, ln2g, ln2b, slotZ);
  transpose_cvt_k<<<dim3(4096 / 32, 1024 / 32), 256, 0, stream>>>(w1, slotW, 1024, 4096);
  gemm_bt<2, 128><<<dim3(32, 32), 256, 0, stream>>>(slotZ, slotW, b1, nullptr,
                                                    nullptr, hbuf, nullptr, nullptr, 4096, 4096, 1024);
  transpose_cvt_k<<<dim3(1024 / 32, 4096 / 32), 256, 0, stream>>>(w2, slotW, 4096, 1024);
  gemm_bt<1, 64><<<dim3(32, 16), 256, 0, stream>>>(hbuf, slotW, b2, x1,
                                                   (float*)d_out, nullptr, nullptr, nullptr, 4096, 1024, 4096);
}